// Round 13
// baseline (532.750 us; speedup 1.0000x reference)
//
#include <hip/hip_runtime.h>
#include <hip/hip_bf16.h>

// MoE Experts v13: g1 = m201-style 8-phase schedule (ring of 8 16KB half-slots,
// half = k-slice 256x32; per phase: reads, 1-half stage, vmcnt(8), barrier,
// sched_barrier, setprio-MFMA x16, barrier). Slot liveness + vmcnt distances
// verified by phase algebra. g2 = v12 proven (256x128 deep-pipe, 2 blk/CU).

#define T_TOK   8192
#define D_MODEL 1024
#define D_FF    4096
#define NE      8
#define MT2     72                 // 256-row tiles
#define ROWS_MAX (MT2 * 256)       // 18432
#define HSLOT   16384
#define LDS_G1  131072             // 8 half-slots
#define BUF2    24576
#define LDS_G2  73728
#define NKT     (D_MODEL / 64)     // 16 K-tiles of 64

typedef float f32x4 __attribute__((ext_vector_type(4)));
typedef short s16x8 __attribute__((ext_vector_type(8)));
typedef short s16x4 __attribute__((ext_vector_type(4)));
typedef unsigned short u16;

__device__ __forceinline__ u16 f2bf(float x) {
  __hip_bfloat16 h = __float2bfloat16(x);   // RNE
  return *reinterpret_cast<u16*>(&h);
}

__device__ __forceinline__ s16x8 cvt8(float4 a, float4 b) {
  s16x8 v;
  v[0] = (short)f2bf(a.x); v[1] = (short)f2bf(a.y);
  v[2] = (short)f2bf(a.z); v[3] = (short)f2bf(a.w);
  v[4] = (short)f2bf(b.x); v[5] = (short)f2bf(b.y);
  v[6] = (short)f2bf(b.z); v[7] = (short)f2bf(b.w);
  return v;
}

__device__ __forceinline__ void gload_lds16(const void* g, void* l) {
  __builtin_amdgcn_global_load_lds((const __attribute__((address_space(1))) void*)g,
                                   (__attribute__((address_space(3))) void*)l,
                                   16, 0, 0);
}

// ---------------- routing compaction ----------------
__global__ void moe_route(const int* __restrict__ sel, const float* __restrict__ rw,
                          int* __restrict__ cnt, int* __restrict__ tidx,
                          float* __restrict__ tw) {
  int t = blockIdx.x * blockDim.x + threadIdx.x;
  if (t >= T_TOK) return;
  int e0 = 0, e1 = 0;
  #pragma unroll
  for (int e = 0; e < NE; ++e) {
    if (sel[t * 16 + e])     e0 = e;
    if (sel[t * 16 + 8 + e]) e1 = e;
  }
  float w0 = rw[2 * t], w1 = rw[2 * t + 1];
  if (e0 == e1) {
    int p = atomicAdd(&cnt[e0], 1);
    tidx[e0 * T_TOK + p] = t; tw[e0 * T_TOK + p] = w0 + w1;
  } else {
    int p = atomicAdd(&cnt[e0], 1);
    tidx[e0 * T_TOK + p] = t; tw[e0 * T_TOK + p] = w0;
    int q = atomicAdd(&cnt[e1], 1);
    tidx[e1 * T_TOK + q] = t; tw[e1 * T_TOK + q] = w1;
  }
}

// ---------------- tile map ----------------
__global__ void moe_tilemap(const int* __restrict__ cnt, const int* __restrict__ tidx,
                            const float* __restrict__ tw, int* __restrict__ te256,
                            int* __restrict__ tokr, float* __restrict__ wr) {
  int off[NE + 1];
  {
    int o = 0;
    #pragma unroll
    for (int e = 0; e < NE; ++e) { off[e] = o; o += (cnt[e] + 255) & ~255; }
    off[NE] = o;
  }
  const int total = off[NE];
  const int gid = blockIdx.x * blockDim.x + threadIdx.x;
  const int stride = gridDim.x * blockDim.x;
  for (int t = gid; t < MT2; t += stride) {
    int r0 = t * 256; int e = -1;
    if (r0 < total) {
      #pragma unroll
      for (int i = NE - 1; i >= 0; --i) if (r0 >= off[i]) { e = i; break; }
    }
    te256[t] = e;
  }
  for (int i = gid; i < ROWS_MAX; i += stride) {
    if (i >= total) { tokr[i] = -1; wr[i] = 0.f; continue; }
    int e = 0;
    #pragma unroll
    for (int k = NE - 1; k >= 0; --k) if (i >= off[k]) { e = k; break; }
    int j = i - off[e];
    int ok = j < cnt[e];
    tokr[i] = ok ? tidx[e * T_TOK + j] : -1;
    wr[i]   = ok ? tw[e * T_TOK + j] : 0.f;
  }
}

// ---------------- gather X rows -> bf16 Xg ----------------
__global__ void moe_gather_x(const float* __restrict__ hs, const int* __restrict__ tokr,
                             u16* __restrict__ Xg) {
  int row = blockIdx.x;
  int tok = tokr[row];
  int c = threadIdx.x * 4;
  u16* dst = Xg + (size_t)row * D_MODEL + c;
  s16x4 o;
  if (tok < 0) {
    o[0] = o[1] = o[2] = o[3] = 0;
  } else {
    float4 v = *(const float4*)(hs + (size_t)tok * D_MODEL + c);
    o[0] = (short)f2bf(v.x); o[1] = (short)f2bf(v.y);
    o[2] = (short)f2bf(v.z); o[3] = (short)f2bf(v.w);
  }
  *(s16x4*)dst = o;
}

// ---------------- f32 -> bf16 weight converts ----------------
__global__ void moe_cvt_w(const float* __restrict__ wi, const float* __restrict__ wo,
                          u16* __restrict__ wib, u16* __restrict__ wob) {
  const size_t NW = (size_t)NE * D_FF * D_MODEL;
  size_t i = ((size_t)blockIdx.x * blockDim.x + threadIdx.x) * 8;
  const float* src; u16* dst;
  if (i < NW) { src = wi + i; dst = wib + i; }
  else        { src = wo + (i - NW); dst = wob + (i - NW); }
  float4 a = *(const float4*)(src);
  float4 b = *(const float4*)(src + 4);
  *(s16x8*)dst = cvt8(a, b);
}

__global__ void moe_cvt_wi_s(const float* __restrict__ wi, u16* __restrict__ wis,
                             int W, int f0) {
  size_t i = ((size_t)blockIdx.x * blockDim.x + threadIdx.x) * 8;
  size_t per = (size_t)W * D_MODEL;
  int e = (int)(i / per); size_t r = i % per;
  const float* src = wi + ((size_t)e * D_FF + f0) * D_MODEL + r;
  float4 a = *(const float4*)src;
  float4 b = *(const float4*)(src + 4);
  *(s16x8*)(wis + i) = cvt8(a, b);
}

__global__ void moe_cvt_wo_s(const float* __restrict__ wo, u16* __restrict__ wos,
                             int W, int f0) {
  size_t i = ((size_t)blockIdx.x * blockDim.x + threadIdx.x) * 8;
  size_t per = (size_t)D_MODEL * W;
  int e = (int)(i / per); size_t r = i % per;
  int row = (int)(r / W), col = (int)(r % W);
  const float* src = wo + ((size_t)e * D_MODEL + row) * D_FF + f0 + col;
  float4 a = *(const float4*)src;
  float4 b = *(const float4*)(src + 4);
  *(s16x8*)(wos + i) = cvt8(a, b);
}

#define MM4(mi, a) \
  acc[mi][0] = __builtin_amdgcn_mfma_f32_16x16x32_bf16(a, bq0, acc[mi][0], 0, 0, 0); \
  acc[mi][1] = __builtin_amdgcn_mfma_f32_16x16x32_bf16(a, bq1, acc[mi][1], 0, 0, 0); \
  acc[mi][2] = __builtin_amdgcn_mfma_f32_16x16x32_bf16(a, bq2, acc[mi][2], 0, 0, 0); \
  acc[mi][3] = __builtin_amdgcn_mfma_f32_16x16x32_bf16(a, bq3, acc[mi][3], 0, 0, 0);

// ---------------- GEMM1: 8-phase 256x256, H = relu(Xg @ Wi^T) ----------------
// Ring of 8 half-slots (16KB): slot(T,h) = ((T&1)*4+h)*16KB, h:0=Ak0,1=Bk0,
// 2=Ak1,3=Bk1 (half = k-slice, 256 rows x 32 cols). Phase p of K-tile T stages
// p0->(T+1).Ak1, p1->(T+1).Bk1, p2->(T+2).Ak0, p3->(T+2).Bk0 (target slot's
// previous tenant is dead: last read >=1 post-MFMA barrier earlier).
// vmcnt(8) each phase => every half has >=8 loads issued after it before its
// first read (verified per-half); prologue vmcnt(4)+barrier.
template <bool FULL>
__global__ __launch_bounds__(512, 1)
void moe_g1(const u16* __restrict__ Xg, const u16* __restrict__ wiP,
            const int* __restrict__ te256, u16* __restrict__ H,
            int W, int f0) {
  extern __shared__ char lds[];
  const int GR = gridDim.x;
  const int task = (blockIdx.x & 7) * (GR >> 3) + (blockIdx.x >> 3);
  const int mt = task % MT2;
  const int nc = task / MT2;
  const int e = te256[mt];
  if (e < 0) return;
  const int grow0 = mt * 256;
  const int fcol = nc * 256;

  const int tid = threadIdx.x;
  const int lane = tid & 63, wv = tid >> 6;
  const int lg = lane >> 4, ll = lane & 15;
  const int wm = wv >> 2, wn = wv & 3;

  // stage addressing: pre-swizzled global source -> linear LDS dest
  const int sw = (tid * 16) ^ (((tid >> 3) & 7) << 4);
  const int srow = sw >> 6, scol = sw & 63;

  const char* gA = (const char*)(Xg + (size_t)grow0 * D_MODEL);
  const char* gB = (const char*)(wiP + (FULL ? ((size_t)e * D_FF + f0 + fcol)
                                             : ((size_t)e * W + fcol)) * D_MODEL);

  f32x4 acc[8][4];
  #pragma unroll
  for (int m = 0; m < 8; ++m)
    #pragma unroll
    for (int n = 0; n < 4; ++n) acc[m][n] = (f32x4){0.f, 0.f, 0.f, 0.f};

  // read helpers: involution f(o) = o ^ (((o>>7)&7)<<4) on within-slot offset
  auto rdA = [&](int slot, int m) -> s16x8 {
    int o = (wm * 128 + m * 16 + ll) * 64 + lg * 16;
    o ^= ((o >> 7) & 7) << 4;
    return *(const s16x8*)(lds + slot + o);
  };
  auto rdB = [&](int slot, int n) -> s16x8 {
    int o = (wn * 64 + n * 16 + ll) * 64 + lg * 16;
    o ^= ((o >> 7) & 7) << 4;
    return *(const s16x8*)(lds + slot + o);
  };
  // stage one half-tile (2 x gload_lds): h = kh*? -> 0=Ak0,1=Bk0,2=Ak1,3=Bk1
  auto stageHalf = [&](int T, int h) {
    if (T >= NKT) return;
    const char* g = (h & 1) ? gB : gA;
    int kh = h >> 1;
    char* dst = lds + (((T & 1) << 2) + h) * HSLOT + tid * 16;
    const char* src = g + (size_t)srow * 2048 + T * 128 + kh * 64 + scol;
    gload_lds16(src, dst);
    gload_lds16(src + (size_t)128 * 2048, dst + 8192);
  };

  // prologue: T0 all 4 halves + T1 Ak0,Bk0; wait first 4 halves landed
  stageHalf(0, 0); stageHalf(0, 1); stageHalf(0, 2); stageHalf(0, 3);
  stageHalf(1, 0); stageHalf(1, 1);
  asm volatile("s_waitcnt vmcnt(4)" ::: "memory");
  asm volatile("s_barrier" ::: "memory");

  for (int T = 0; T < NKT; ++T) {
    const int base = ((T & 1) << 2) * HSLOT;
    const int sA0 = base, sB0 = base + HSLOT;
    const int sA1 = base + 2 * HSLOT, sB1 = base + 3 * HSLOT;
    s16x8 bq0, bq1, bq2, bq3, a0, a1, a2, a3;

    // ---- phase 0: k0, m0-3 ----
    bq0 = rdB(sB0, 0); bq1 = rdB(sB0, 1); bq2 = rdB(sB0, 2); bq3 = rdB(sB0, 3);
    a0 = rdA(sA0, 0); a1 = rdA(sA0, 1); a2 = rdA(sA0, 2); a3 = rdA(sA0, 3);
    stageHalf(T + 1, 2);
    asm volatile("s_waitcnt vmcnt(8)" ::: "memory");
    asm volatile("s_barrier" ::: "memory");
    __builtin_amdgcn_sched_barrier(0);
    __builtin_amdgcn_s_setprio(1);
    MM4(0, a0) MM4(1, a1) MM4(2, a2) MM4(3, a3)
    __builtin_amdgcn_s_setprio(0);
    asm volatile("s_barrier" ::: "memory");

    // ---- phase 1: k0, m4-7 ----
    a0 = rdA(sA0, 4); a1 = rdA(sA0, 5); a2 = rdA(sA0, 6); a3 = rdA(sA0, 7);
    stageHalf(T + 1, 3);
    asm volatile("s_waitcnt vmcnt(8)" ::: "memory");
    asm volatile("s_barrier" ::: "memory");
    __builtin_amdgcn_sched_barrier(0);
    __builtin_amdgcn_s_setprio(1);
    MM4(4, a0) MM4(5, a1) MM4(6, a2) MM4(7, a3)
    __builtin_amdgcn_s_setprio(0);
    asm volatile("s_barrier" ::: "memory");

    // ---- phase 2: k1, m0-3 ----
    bq0 = rdB(sB1, 0); bq1 = rdB(sB1, 1); bq2 = rdB(sB1, 2); bq3 = rdB(sB1, 3);
    a0 = rdA(sA1, 0); a1 = rdA(sA1, 1); a2 = rdA(sA1, 2); a3 = rdA(sA1, 3);
    stageHalf(T + 2, 0);
    asm volatile("s_waitcnt vmcnt(8)" ::: "memory");
    asm volatile("s_barrier" ::: "memory");
    __builtin_amdgcn_sched_barrier(0);
    __builtin_amdgcn_s_setprio(1);
    MM4(0, a0) MM4(1, a1) MM4(2, a2) MM4(3, a3)
    __builtin_amdgcn_s_setprio(0);
    asm volatile("s_barrier" ::: "memory");

    // ---- phase 3: k1, m4-7 ----
    a0 = rdA(sA1, 4); a1 = rdA(sA1, 5); a2 = rdA(sA1, 6); a3 = rdA(sA1, 7);
    stageHalf(T + 2, 1);
    asm volatile("s_waitcnt vmcnt(8)" ::: "memory");
    asm volatile("s_barrier" ::: "memory");
    __builtin_amdgcn_sched_barrier(0);
    __builtin_amdgcn_s_setprio(1);
    MM4(4, a0) MM4(5, a1) MM4(6, a2) MM4(7, a3)
    __builtin_amdgcn_s_setprio(0);
    asm volatile("s_barrier" ::: "memory");
  }

  #pragma unroll
  for (int mf = 0; mf < 8; ++mf) {
    #pragma unroll
    for (int r = 0; r < 4; ++r) {
      int row = grow0 + wm * 128 + mf * 16 + lg * 4 + r;
      u16* hp = H + (size_t)row * W + fcol + wn * 64 + ll;
      #pragma unroll
      for (int nf = 0; nf < 4; ++nf) {
        float v = acc[mf][nf][r];
        hp[nf * 16] = f2bf(v > 0.f ? v : 0.f);
      }
    }
  }
}

// ---------------- GEMM2 (v12 proven): 256x128 deep-pipe ----------------
template <bool FULL>
__global__ __launch_bounds__(512, 4)
void moe_g2(const u16* __restrict__ H, const u16* __restrict__ woP,
            const int* __restrict__ te256, const int* __restrict__ tokr,
            const float* __restrict__ wr, float* __restrict__ out,
            int W, int f0, int KCH) {
  extern __shared__ char lds[];
  const int GR = gridDim.x;
  const int task = (blockIdx.x & 7) * (GR >> 3) + (blockIdx.x >> 3);
  const int dc = task & 7;
  const int rest = task >> 3;
  const int mt = rest % MT2;
  const int kc = rest / MT2;
  const int e = te256[mt];
  if (e < 0) return;
  const int grow0 = mt * 256;
  const int dcol0 = dc * 128;

  const int tid = threadIdx.x;
  const int lane = tid & 63, wv = tid >> 6;
  const int lg = lane >> 4, ll = lane & 15;
  const int wm = wv >> 1, wn = wv & 1;

  const int sw = (tid * 16) ^ (((tid >> 3) & 7) << 4);
  const int srow = sw >> 6, scol = sw & 63;
  const int inner = (ll * 64 + lg * 16) ^ (((ll >> 1) & 7) << 4);

  const size_t pA = (size_t)W * 2;
  const size_t pB = (FULL ? (size_t)D_FF : (size_t)W) * 2;
  const char* gA = (const char*)(H + (size_t)grow0 * W) + (size_t)kc * KCH * 2;
  const char* gB = (const char*)(woP + ((size_t)e * D_MODEL + dcol0) * (pB / 2)
                                 + (FULL ? f0 : 0)) + (size_t)kc * KCH * 2;

  f32x4 acc[4][4];
  #pragma unroll
  for (int m = 0; m < 4; ++m)
    #pragma unroll
    for (int n = 0; n < 4; ++n) acc[m][n] = (f32x4){0.f, 0.f, 0.f, 0.f};

  auto stageA = [&](int kb, char* lbuf) {
    #pragma unroll
    for (int j = 0; j < 2; ++j)
      gload_lds16(gA + (size_t)(j * 128 + srow) * pA + kb + scol,
                  lbuf + j * 8192 + tid * 16);
  };
  auto stageB = [&](int kb, char* lbuf) {
    gload_lds16(gB + (size_t)srow * pB + kb + scol, lbuf + 16384 + tid * 16);
  };

  const int NT = KCH / 32;
  stageA(0, lds);   stageB(0, lds);
  stageA(64, lds + BUF2); stageB(64, lds + BUF2);
  int bufi = 0;
  for (int t = 0; t < NT; ++t) {
    if (t < NT - 1) { asm volatile("s_waitcnt vmcnt(3)" ::: "memory"); }
    else            { asm volatile("s_waitcnt vmcnt(0)" ::: "memory"); }
    asm volatile("s_barrier" ::: "memory");
    const char* la = lds + bufi * BUF2 + wm * 4096;
    const char* lb = lds + bufi * BUF2 + 16384 + wn * 4096;
    int b2 = bufi + 2; if (b2 >= 3) b2 -= 3;
    const bool pf = (t + 2 < NT);
    s16x8 bq0 = *(const s16x8*)(lb + 0 * 1024 + inner);
    s16x8 bq1 = *(const s16x8*)(lb + 1 * 1024 + inner);
    s16x8 bq2 = *(const s16x8*)(lb + 2 * 1024 + inner);
    s16x8 bq3 = *(const s16x8*)(lb + 3 * 1024 + inner);
    {
      s16x8 a0 = *(const s16x8*)(la + 0 * 1024 + inner);
      s16x8 a1 = *(const s16x8*)(la + 1 * 1024 + inner);
      if (pf) stageA((t + 2) * 64, lds + b2 * BUF2);
      __builtin_amdgcn_s_setprio(1);
      MM4(0, a0) MM4(1, a1)
      __builtin_amdgcn_s_setprio(0);
    }
    {
      s16x8 a2 = *(const s16x8*)(la + 2 * 1024 + inner);
      s16x8 a3 = *(const s16x8*)(la + 3 * 1024 + inner);
      if (pf) stageB((t + 2) * 64, lds + b2 * BUF2);
      __builtin_amdgcn_s_setprio(1);
      MM4(2, a2) MM4(3, a3)
      __builtin_amdgcn_s_setprio(0);
    }
    bufi += 1; if (bufi >= 3) bufi -= 3;
  }

  #pragma unroll
  for (int mf = 0; mf < 4; ++mf) {
    #pragma unroll
    for (int r = 0; r < 4; ++r) {
      int row = grow0 + wm * 64 + mf * 16 + lg * 4 + r;
      int tok = tokr[row];
      if (tok >= 0) {
        float w = wr[row];
        float* op = out + (size_t)tok * D_MODEL + dcol0 + wn * 64 + ll;
        #pragma unroll
        for (int nf = 0; nf < 4; ++nf)
          atomicAdd(op + nf * 16, acc[mf][nf][r] * w);
      }
    }
  }
}

// ---------------- host ----------------
extern "C" void kernel_launch(void* const* d_in, const int* in_sizes, int n_in,
                              void* d_out, int out_size, void* d_ws, size_t ws_size,
                              hipStream_t stream) {
  const float* hs  = (const float*)d_in[0];
  const int*   sel = (const int*)d_in[1];
  const float* rw  = (const float*)d_in[2];
  const float* wi  = (const float*)d_in[3];
  const float* wo  = (const float*)d_in[4];
  float* out = (float*)d_out;

  const size_t NW   = (size_t)NE * D_FF * D_MODEL;
  const size_t CTRL = 1u << 20;
  const size_t WB   = 2 * NW * sizeof(u16);
  const size_t XGB  = (size_t)ROWS_MAX * D_MODEL * 2;

  bool FULLW = true; int W = D_FF;
  {
    bool found = false;
    for (int f : {1, 2, 4, 8, 16}) {
      int Wc = D_FF / f;
      size_t need = CTRL + WB + XGB + (size_t)ROWS_MAX * Wc * 2;
      if (need <= ws_size) { FULLW = true; W = Wc; found = true; break; }
    }
    if (!found) {
      for (int Wc : {1024, 512, 256}) {
        size_t sl = (size_t)2 * NE * Wc * D_MODEL * 2;
        size_t need = CTRL + sl + XGB + (size_t)ROWS_MAX * Wc * 2;
        if (need <= ws_size) { FULLW = false; W = Wc; break; }
      }
    }
  }
  const int FS = D_FF / W;

  size_t off = 0;
  auto take = [&](size_t b) -> char* {
    char* r = (char*)d_ws + off; off = (off + b + 255) & ~(size_t)255; return r;
  };
  int*   tidx = (int*)take((size_t)NE * T_TOK * 4);
  float* tw   = (float*)take((size_t)NE * T_TOK * 4);
  int*   tokr = (int*)take((size_t)ROWS_MAX * 4);
  float* wrr  = (float*)take((size_t)ROWS_MAX * 4);
  int*   te2  = (int*)take(MT2 * 4);
  int*   cnt  = (int*)take(256);
  off = CTRL;
  u16 *wiP, *woP;
  if (FULLW) { wiP = (u16*)take(NW * 2); woP = (u16*)take(NW * 2); }
  else       { wiP = (u16*)take((size_t)NE * W * D_MODEL * 2);
               woP = (u16*)take((size_t)NE * D_MODEL * W * 2); }
  u16* Xg   = (u16*)take(XGB);
  u16* Hbuf = (u16*)take((size_t)ROWS_MAX * W * 2);

  hipMemsetAsync(cnt, 0, 256, stream);
  hipMemsetAsync(d_out, 0, (size_t)out_size * sizeof(float), stream);
  moe_route<<<T_TOK / 256, 256, 0, stream>>>(sel, rw, cnt, tidx, tw);
  moe_tilemap<<<64, 256, 0, stream>>>(cnt, tidx, tw, te2, tokr, wrr);
  moe_gather_x<<<ROWS_MAX, 256, 0, stream>>>(hs, tokr, Xg);
  if (FULLW)
    moe_cvt_w<<<(int)(2 * NW / 8 / 256), 256, 0, stream>>>(wi, wo, wiP, woP);

  hipFuncSetAttribute(reinterpret_cast<const void*>(&moe_g1<true>),
                      hipFuncAttributeMaxDynamicSharedMemorySize, LDS_G1);
  hipFuncSetAttribute(reinterpret_cast<const void*>(&moe_g1<false>),
                      hipFuncAttributeMaxDynamicSharedMemorySize, LDS_G1);
  hipFuncSetAttribute(reinterpret_cast<const void*>(&moe_g2<true>),
                      hipFuncAttributeMaxDynamicSharedMemorySize, LDS_G2);
  hipFuncSetAttribute(reinterpret_cast<const void*>(&moe_g2<false>),
                      hipFuncAttributeMaxDynamicSharedMemorySize, LDS_G2);

  const int KCH = W / 2;
  const int g1grid = MT2 * (W / 256);
  const int g2grid = MT2 * 8 * 2;
  const int cvtblk = (int)(((size_t)NE * W * D_MODEL / 8) / 256);

  for (int p = 0; p < FS; ++p) {
    const int f0 = p * W;
    if (!FULLW) {
      moe_cvt_wi_s<<<cvtblk, 256, 0, stream>>>(wi, wiP, W, f0);
      moe_cvt_wo_s<<<cvtblk, 256, 0, stream>>>(wo, woP, W, f0);
    }
    if (FULLW) {
      moe_g1<true><<<g1grid, 512, LDS_G1, stream>>>(Xg, wiP, te2, Hbuf, W, f0);
      moe_g2<true><<<g2grid, 512, LDS_G2, stream>>>(Hbuf, woP, te2, tokr, wrr,
                                                    out, W, f0, KCH);
    } else {
      moe_g1<false><<<g1grid, 512, LDS_G1, stream>>>(Xg, wiP, te2, Hbuf, W, f0);
      moe_g2<false><<<g2grid, 512, LDS_G2, stream>>>(Hbuf, woP, te2, tokr, wrr,
                                                     out, W, f0, KCH);
    }
  }
}

// Round 15
// 532.403 us; speedup vs baseline: 1.0007x; 1.0007x over previous
//
#include <hip/hip_runtime.h>
#include <hip/hip_bf16.h>

// MoE Experts v15: v14 with the vmcnt placed BEFORE the protected readers
// (m201 discipline): prologue vmcnt(4)+barrier; one counted vmcnt per K-tile
// at p3 (protects tile T+1's reads, separated by 2 barriers); no other waits.
// v14's bug: its only wait sat AFTER p0's ds_reads, so tile T's own halves
// (explicitly left outstanding by the previous wait) could be read un-landed.
// g2 = v12 proven (256x128 deep-pipe, 2 blk/CU).

#define T_TOK   8192
#define D_MODEL 1024
#define D_FF    4096
#define NE      8
#define MT2     72                 // 256-row tiles
#define ROWS_MAX (MT2 * 256)       // 18432
#define HSLOT   16384
#define LDS_G1  131072             // 8 half-slots
#define BUF2    24576
#define LDS_G2  73728
#define NKT     (D_MODEL / 64)     // 16 K-tiles of 64

typedef float f32x4 __attribute__((ext_vector_type(4)));
typedef short s16x8 __attribute__((ext_vector_type(8)));
typedef short s16x4 __attribute__((ext_vector_type(4)));
typedef unsigned short u16;

__device__ __forceinline__ u16 f2bf(float x) {
  __hip_bfloat16 h = __float2bfloat16(x);   // RNE
  return *reinterpret_cast<u16*>(&h);
}

__device__ __forceinline__ s16x8 cvt8(float4 a, float4 b) {
  s16x8 v;
  v[0] = (short)f2bf(a.x); v[1] = (short)f2bf(a.y);
  v[2] = (short)f2bf(a.z); v[3] = (short)f2bf(a.w);
  v[4] = (short)f2bf(b.x); v[5] = (short)f2bf(b.y);
  v[6] = (short)f2bf(b.z); v[7] = (short)f2bf(b.w);
  return v;
}

__device__ __forceinline__ void gload_lds16(const void* g, void* l) {
  __builtin_amdgcn_global_load_lds((const __attribute__((address_space(1))) void*)g,
                                   (__attribute__((address_space(3))) void*)l,
                                   16, 0, 0);
}

// ---------------- routing compaction ----------------
__global__ void moe_route(const int* __restrict__ sel, const float* __restrict__ rw,
                          int* __restrict__ cnt, int* __restrict__ tidx,
                          float* __restrict__ tw) {
  int t = blockIdx.x * blockDim.x + threadIdx.x;
  if (t >= T_TOK) return;
  int e0 = 0, e1 = 0;
  #pragma unroll
  for (int e = 0; e < NE; ++e) {
    if (sel[t * 16 + e])     e0 = e;
    if (sel[t * 16 + 8 + e]) e1 = e;
  }
  float w0 = rw[2 * t], w1 = rw[2 * t + 1];
  if (e0 == e1) {
    int p = atomicAdd(&cnt[e0], 1);
    tidx[e0 * T_TOK + p] = t; tw[e0 * T_TOK + p] = w0 + w1;
  } else {
    int p = atomicAdd(&cnt[e0], 1);
    tidx[e0 * T_TOK + p] = t; tw[e0 * T_TOK + p] = w0;
    int q = atomicAdd(&cnt[e1], 1);
    tidx[e1 * T_TOK + q] = t; tw[e1 * T_TOK + q] = w1;
  }
}

// ---------------- tile map ----------------
__global__ void moe_tilemap(const int* __restrict__ cnt, const int* __restrict__ tidx,
                            const float* __restrict__ tw, int* __restrict__ te256,
                            int* __restrict__ tokr, float* __restrict__ wr) {
  int off[NE + 1];
  {
    int o = 0;
    #pragma unroll
    for (int e = 0; e < NE; ++e) { off[e] = o; o += (cnt[e] + 255) & ~255; }
    off[NE] = o;
  }
  const int total = off[NE];
  const int gid = blockIdx.x * blockDim.x + threadIdx.x;
  const int stride = gridDim.x * blockDim.x;
  for (int t = gid; t < MT2; t += stride) {
    int r0 = t * 256; int e = -1;
    if (r0 < total) {
      #pragma unroll
      for (int i = NE - 1; i >= 0; --i) if (r0 >= off[i]) { e = i; break; }
    }
    te256[t] = e;
  }
  for (int i = gid; i < ROWS_MAX; i += stride) {
    if (i >= total) { tokr[i] = -1; wr[i] = 0.f; continue; }
    int e = 0;
    #pragma unroll
    for (int k = NE - 1; k >= 0; --k) if (i >= off[k]) { e = k; break; }
    int j = i - off[e];
    int ok = j < cnt[e];
    tokr[i] = ok ? tidx[e * T_TOK + j] : -1;
    wr[i]   = ok ? tw[e * T_TOK + j] : 0.f;
  }
}

// ---------------- gather X rows -> bf16 Xg ----------------
__global__ void moe_gather_x(const float* __restrict__ hs, const int* __restrict__ tokr,
                             u16* __restrict__ Xg) {
  int row = blockIdx.x;
  int tok = tokr[row];
  int c = threadIdx.x * 4;
  u16* dst = Xg + (size_t)row * D_MODEL + c;
  s16x4 o;
  if (tok < 0) {
    o[0] = o[1] = o[2] = o[3] = 0;
  } else {
    float4 v = *(const float4*)(hs + (size_t)tok * D_MODEL + c);
    o[0] = (short)f2bf(v.x); o[1] = (short)f2bf(v.y);
    o[2] = (short)f2bf(v.z); o[3] = (short)f2bf(v.w);
  }
  *(s16x4*)dst = o;
}

// ---------------- f32 -> bf16 weight converts ----------------
__global__ void moe_cvt_w(const float* __restrict__ wi, const float* __restrict__ wo,
                          u16* __restrict__ wib, u16* __restrict__ wob) {
  const size_t NW = (size_t)NE * D_FF * D_MODEL;
  size_t i = ((size_t)blockIdx.x * blockDim.x + threadIdx.x) * 8;
  const float* src; u16* dst;
  if (i < NW) { src = wi + i; dst = wib + i; }
  else        { src = wo + (i - NW); dst = wob + (i - NW); }
  float4 a = *(const float4*)(src);
  float4 b = *(const float4*)(src + 4);
  *(s16x8*)dst = cvt8(a, b);
}

__global__ void moe_cvt_wi_s(const float* __restrict__ wi, u16* __restrict__ wis,
                             int W, int f0) {
  size_t i = ((size_t)blockIdx.x * blockDim.x + threadIdx.x) * 8;
  size_t per = (size_t)W * D_MODEL;
  int e = (int)(i / per); size_t r = i % per;
  const float* src = wi + ((size_t)e * D_FF + f0) * D_MODEL + r;
  float4 a = *(const float4*)src;
  float4 b = *(const float4*)(src + 4);
  *(s16x8*)(wis + i) = cvt8(a, b);
}

__global__ void moe_cvt_wo_s(const float* __restrict__ wo, u16* __restrict__ wos,
                             int W, int f0) {
  size_t i = ((size_t)blockIdx.x * blockDim.x + threadIdx.x) * 8;
  size_t per = (size_t)D_MODEL * W;
  int e = (int)(i / per); size_t r = i % per;
  int row = (int)(r / W), col = (int)(r % W);
  const float* src = wo + ((size_t)e * D_MODEL + row) * D_FF + f0 + col;
  float4 a = *(const float4*)src;
  float4 b = *(const float4*)(src + 4);
  *(s16x8*)(wos + i) = cvt8(a, b);
}

#define MM4(mi, a) \
  acc[mi][0] = __builtin_amdgcn_mfma_f32_16x16x32_bf16(a, bq0, acc[mi][0], 0, 0, 0); \
  acc[mi][1] = __builtin_amdgcn_mfma_f32_16x16x32_bf16(a, bq1, acc[mi][1], 0, 0, 0); \
  acc[mi][2] = __builtin_amdgcn_mfma_f32_16x16x32_bf16(a, bq2, acc[mi][2], 0, 0, 0); \
  acc[mi][3] = __builtin_amdgcn_mfma_f32_16x16x32_bf16(a, bq3, acc[mi][3], 0, 0, 0);

// ---------------- GEMM1: 8-phase 256x256, wait-before-readers ----------------
// Ring: slot(T,h) = ((T&1)*4+h)*16KB; h: 0=Ak0,1=Bk0,2=Ak1,3=Bk1.
// Stage map: p0->(T+1,Ak1), p1->(T+1,Bk1), p2->(T+2,Ak0), p3->(T+2,Bk0).
// Tile T+1's halves are staged at T-1.p2/p3 + T.p0/p1; at T.p3 (after its
// stage) loads newer than (T+1,Bk1) = T.p2 + T.p3 stages = 4 (or 0 when
// T+2>=NKT skips them) => vmcnt(4|0) at T.p3, two barriers before T+1.p0's
// reads. Prologue: 12 loads, newer-than-(T0,Bk1) = T1's 4 => vmcnt(4)+barrier.
template <bool FULL>
__global__ __launch_bounds__(512, 1)
void moe_g1(const u16* __restrict__ Xg, const u16* __restrict__ wiP,
            const int* __restrict__ te256, u16* __restrict__ H,
            int W, int f0) {
  extern __shared__ char lds[];
  const int GR = gridDim.x;
  const int task = (blockIdx.x & 7) * (GR >> 3) + (blockIdx.x >> 3);
  const int mt = task % MT2;
  const int nc = task / MT2;
  const int e = te256[mt];
  if (e < 0) return;
  const int grow0 = mt * 256;
  const int fcol = nc * 256;

  const int tid = threadIdx.x;
  const int lane = tid & 63, wv = tid >> 6;
  const int lg = lane >> 4, ll = lane & 15;
  const int wm = wv >> 2, wn = wv & 3;

  const int sw = (tid * 16) ^ (((tid >> 3) & 7) << 4);
  const int srow = sw >> 6, scol = sw & 63;

  const char* gA = (const char*)(Xg + (size_t)grow0 * D_MODEL);
  const char* gB = (const char*)(wiP + (FULL ? ((size_t)e * D_FF + f0 + fcol)
                                             : ((size_t)e * W + fcol)) * D_MODEL);

  f32x4 acc[8][4];
  #pragma unroll
  for (int m = 0; m < 8; ++m)
    #pragma unroll
    for (int n = 0; n < 4; ++n) acc[m][n] = (f32x4){0.f, 0.f, 0.f, 0.f};

  auto rdA = [&](int slot, int m) -> s16x8 {
    int o = (wm * 128 + m * 16 + ll) * 64 + lg * 16;
    o ^= ((o >> 7) & 7) << 4;
    return *(const s16x8*)(lds + slot + o);
  };
  auto rdB = [&](int slot, int n) -> s16x8 {
    int o = (wn * 64 + n * 16 + ll) * 64 + lg * 16;
    o ^= ((o >> 7) & 7) << 4;
    return *(const s16x8*)(lds + slot + o);
  };
  auto stageHalf = [&](int T, int h) {
    if (T >= NKT) return;
    const char* g = (h & 1) ? gB : gA;
    int kh = h >> 1;
    char* dst = lds + (((T & 1) << 2) + h) * HSLOT + tid * 16;
    const char* src = g + (size_t)srow * 2048 + T * 128 + kh * 64 + scol;
    gload_lds16(src, dst);
    gload_lds16(src + (size_t)128 * 2048, dst + 8192);
  };

  // prologue: T0 h0..h3 (8 loads) + T1 Ak0,Bk0 (4 loads); tile 0 landed when
  // <=4 newest (T1's) remain outstanding.
  stageHalf(0, 0); stageHalf(0, 1); stageHalf(0, 2); stageHalf(0, 3);
  stageHalf(1, 0); stageHalf(1, 1);
  asm volatile("s_waitcnt vmcnt(4)" ::: "memory");
  asm volatile("s_barrier" ::: "memory");

  for (int T = 0; T < NKT; ++T) {
    const int base = ((T & 1) << 2) * HSLOT;
    const int sA0 = base, sB0 = base + HSLOT;
    const int sA1 = base + 2 * HSLOT, sB1 = base + 3 * HSLOT;
    s16x8 bq0, bq1, bq2, bq3, a0, a1, a2, a3;

    // ---- phase 0: k0, m0-3 | stage (T+1,Ak1) ----
    bq0 = rdB(sB0, 0); bq1 = rdB(sB0, 1); bq2 = rdB(sB0, 2); bq3 = rdB(sB0, 3);
    a0 = rdA(sA0, 0); a1 = rdA(sA0, 1); a2 = rdA(sA0, 2); a3 = rdA(sA0, 3);
    stageHalf(T + 1, 2);
    asm volatile("s_barrier" ::: "memory");
    __builtin_amdgcn_sched_barrier(0);
    __builtin_amdgcn_s_setprio(1);
    MM4(0, a0) MM4(1, a1) MM4(2, a2) MM4(3, a3)
    __builtin_amdgcn_s_setprio(0);
    asm volatile("s_barrier" ::: "memory");

    // ---- phase 1: k0, m4-7 | stage (T+1,Bk1) ----
    a0 = rdA(sA0, 4); a1 = rdA(sA0, 5); a2 = rdA(sA0, 6); a3 = rdA(sA0, 7);
    stageHalf(T + 1, 3);
    asm volatile("s_barrier" ::: "memory");
    __builtin_amdgcn_sched_barrier(0);
    __builtin_amdgcn_s_setprio(1);
    MM4(4, a0) MM4(5, a1) MM4(6, a2) MM4(7, a3)
    __builtin_amdgcn_s_setprio(0);
    asm volatile("s_barrier" ::: "memory");

    // ---- phase 2: k1, m0-3 | stage (T+2,Ak0) ----
    bq0 = rdB(sB1, 0); bq1 = rdB(sB1, 1); bq2 = rdB(sB1, 2); bq3 = rdB(sB1, 3);
    a0 = rdA(sA1, 0); a1 = rdA(sA1, 1); a2 = rdA(sA1, 2); a3 = rdA(sA1, 3);
    stageHalf(T + 2, 0);
    asm volatile("s_barrier" ::: "memory");
    __builtin_amdgcn_sched_barrier(0);
    __builtin_amdgcn_s_setprio(1);
    MM4(0, a0) MM4(1, a1) MM4(2, a2) MM4(3, a3)
    __builtin_amdgcn_s_setprio(0);
    asm volatile("s_barrier" ::: "memory");

    // ---- phase 3: k1, m4-7 | stage (T+2,Bk0) | per-tile counted vmcnt ----
    a0 = rdA(sA1, 4); a1 = rdA(sA1, 5); a2 = rdA(sA1, 6); a3 = rdA(sA1, 7);
    stageHalf(T + 2, 1);
    if (T + 1 < NKT) {
      if (T + 2 < NKT) { asm volatile("s_waitcnt vmcnt(4)" ::: "memory"); }
      else             { asm volatile("s_waitcnt vmcnt(0)" ::: "memory"); }
    }
    asm volatile("s_barrier" ::: "memory");
    __builtin_amdgcn_sched_barrier(0);
    __builtin_amdgcn_s_setprio(1);
    MM4(4, a0) MM4(5, a1) MM4(6, a2) MM4(7, a3)
    __builtin_amdgcn_s_setprio(0);
    asm volatile("s_barrier" ::: "memory");
  }

  #pragma unroll
  for (int mf = 0; mf < 8; ++mf) {
    #pragma unroll
    for (int r = 0; r < 4; ++r) {
      int row = grow0 + wm * 128 + mf * 16 + lg * 4 + r;
      u16* hp = H + (size_t)row * W + fcol + wn * 64 + ll;
      #pragma unroll
      for (int nf = 0; nf < 4; ++nf) {
        float v = acc[mf][nf][r];
        hp[nf * 16] = f2bf(v > 0.f ? v : 0.f);
      }
    }
  }
}

// ---------------- GEMM2 (v12 proven): 256x128 deep-pipe ----------------
template <bool FULL>
__global__ __launch_bounds__(512, 4)
void moe_g2(const u16* __restrict__ H, const u16* __restrict__ woP,
            const int* __restrict__ te256, const int* __restrict__ tokr,
            const float* __restrict__ wr, float* __restrict__ out,
            int W, int f0, int KCH) {
  extern __shared__ char lds[];
  const int GR = gridDim.x;
  const int task = (blockIdx.x & 7) * (GR >> 3) + (blockIdx.x >> 3);
  const int dc = task & 7;
  const int rest = task >> 3;
  const int mt = rest % MT2;
  const int kc = rest / MT2;
  const int e = te256[mt];
  if (e < 0) return;
  const int grow0 = mt * 256;
  const int dcol0 = dc * 128;

  const int tid = threadIdx.x;
  const int lane = tid & 63, wv = tid >> 6;
  const int lg = lane >> 4, ll = lane & 15;
  const int wm = wv >> 1, wn = wv & 1;

  const int sw = (tid * 16) ^ (((tid >> 3) & 7) << 4);
  const int srow = sw >> 6, scol = sw & 63;
  const int inner = (ll * 64 + lg * 16) ^ (((ll >> 1) & 7) << 4);

  const size_t pA = (size_t)W * 2;
  const size_t pB = (FULL ? (size_t)D_FF : (size_t)W) * 2;
  const char* gA = (const char*)(H + (size_t)grow0 * W) + (size_t)kc * KCH * 2;
  const char* gB = (const char*)(woP + ((size_t)e * D_MODEL + dcol0) * (pB / 2)
                                 + (FULL ? f0 : 0)) + (size_t)kc * KCH * 2;

  f32x4 acc[4][4];
  #pragma unroll
  for (int m = 0; m < 4; ++m)
    #pragma unroll
    for (int n = 0; n < 4; ++n) acc[m][n] = (f32x4){0.f, 0.f, 0.f, 0.f};

  auto stageA = [&](int kb, char* lbuf) {
    #pragma unroll
    for (int j = 0; j < 2; ++j)
      gload_lds16(gA + (size_t)(j * 128 + srow) * pA + kb + scol,
                  lbuf + j * 8192 + tid * 16);
  };
  auto stageB = [&](int kb, char* lbuf) {
    gload_lds16(gB + (size_t)srow * pB + kb + scol, lbuf + 16384 + tid * 16);
  };

  const int NT = KCH / 32;
  stageA(0, lds);   stageB(0, lds);
  stageA(64, lds + BUF2); stageB(64, lds + BUF2);
  int bufi = 0;
  for (int t = 0; t < NT; ++t) {
    if (t < NT - 1) { asm volatile("s_waitcnt vmcnt(3)" ::: "memory"); }
    else            { asm volatile("s_waitcnt vmcnt(0)" ::: "memory"); }
    asm volatile("s_barrier" ::: "memory");
    const char* la = lds + bufi * BUF2 + wm * 4096;
    const char* lb = lds + bufi * BUF2 + 16384 + wn * 4096;
    int b2 = bufi + 2; if (b2 >= 3) b2 -= 3;
    const bool pf = (t + 2 < NT);
    s16x8 bq0 = *(const s16x8*)(lb + 0 * 1024 + inner);
    s16x8 bq1 = *(const s16x8*)(lb + 1 * 1024 + inner);
    s16x8 bq2 = *(const s16x8*)(lb + 2 * 1024 + inner);
    s16x8 bq3 = *(const s16x8*)(lb + 3 * 1024 + inner);
    {
      s16x8 a0 = *(const s16x8*)(la + 0 * 1024 + inner);
      s16x8 a1 = *(const s16x8*)(la + 1 * 1024 + inner);
      if (pf) stageA((t + 2) * 64, lds + b2 * BUF2);
      __builtin_amdgcn_s_setprio(1);
      MM4(0, a0) MM4(1, a1)
      __builtin_amdgcn_s_setprio(0);
    }
    {
      s16x8 a2 = *(const s16x8*)(la + 2 * 1024 + inner);
      s16x8 a3 = *(const s16x8*)(la + 3 * 1024 + inner);
      if (pf) stageB((t + 2) * 64, lds + b2 * BUF2);
      __builtin_amdgcn_s_setprio(1);
      MM4(2, a2) MM4(3, a3)
      __builtin_amdgcn_s_setprio(0);
    }
    bufi += 1; if (bufi >= 3) bufi -= 3;
  }

  #pragma unroll
  for (int mf = 0; mf < 4; ++mf) {
    #pragma unroll
    for (int r = 0; r < 4; ++r) {
      int row = grow0 + wm * 64 + mf * 16 + lg * 4 + r;
      int tok = tokr[row];
      if (tok >= 0) {
        float w = wr[row];
        float* op = out + (size_t)tok * D_MODEL + dcol0 + wn * 64 + ll;
        #pragma unroll
        for (int nf = 0; nf < 4; ++nf)
          atomicAdd(op + nf * 16, acc[mf][nf][r] * w);
      }
    }
  }
}

// ---------------- host ----------------
extern "C" void kernel_launch(void* const* d_in, const int* in_sizes, int n_in,
                              void* d_out, int out_size, void* d_ws, size_t ws_size,
                              hipStream_t stream) {
  const float* hs  = (const float*)d_in[0];
  const int*   sel = (const int*)d_in[1];
  const float* rw  = (const float*)d_in[2];
  const float* wi  = (const float*)d_in[3];
  const float* wo  = (const float*)d_in[4];
  float* out = (float*)d_out;

  const size_t NW   = (size_t)NE * D_FF * D_MODEL;
  const size_t CTRL = 1u << 20;
  const size_t WB   = 2 * NW * sizeof(u16);
  const size_t XGB  = (size_t)ROWS_MAX * D_MODEL * 2;

  bool FULLW = true; int W = D_FF;
  {
    bool found = false;
    for (int f : {1, 2, 4, 8, 16}) {
      int Wc = D_FF / f;
      size_t need = CTRL + WB + XGB + (size_t)ROWS_MAX * Wc * 2;
      if (need <= ws_size) { FULLW = true; W = Wc; found = true; break; }
    }
    if (!found) {
      for (int Wc : {1024, 512, 256}) {
        size_t sl = (size_t)2 * NE * Wc * D_MODEL * 2;
        size_t need = CTRL + sl + XGB + (size_t)ROWS_MAX * Wc * 2;
        if (need <= ws_size) { FULLW = false; W = Wc; break; }
      }
    }
  }
  const int FS = D_FF / W;

  size_t off = 0;
  auto take = [&](size_t b) -> char* {
    char* r = (char*)d_ws + off; off = (off + b + 255) & ~(size_t)255; return r;
  };
  int*   tidx = (int*)take((size_t)NE * T_TOK * 4);
  float* tw   = (float*)take((size_t)NE * T_TOK * 4);
  int*   tokr = (int*)take((size_t)ROWS_MAX * 4);
  float* wrr  = (float*)take((size_t)ROWS_MAX * 4);
  int*   te2  = (int*)take(MT2 * 4);
  int*   cnt  = (int*)take(256);
  off = CTRL;
  u16 *wiP, *woP;
  if (FULLW) { wiP = (u16*)take(NW * 2); woP = (u16*)take(NW * 2); }
  else       { wiP = (u16*)take((size_t)NE * W * D_MODEL * 2);
               woP = (u16*)take((size_t)NE * D_MODEL * W * 2); }
  u16* Xg   = (u16*)take(XGB);
  u16* Hbuf = (u16*)take((size_t)ROWS_MAX * W * 2);

  hipMemsetAsync(cnt, 0, 256, stream);
  hipMemsetAsync(d_out, 0, (size_t)out_size * sizeof(float), stream);
  moe_route<<<T_TOK / 256, 256, 0, stream>>>(sel, rw, cnt, tidx, tw);
  moe_tilemap<<<64, 256, 0, stream>>>(cnt, tidx, tw, te2, tokr, wrr);
  moe_gather_x<<<ROWS_MAX, 256, 0, stream>>>(hs, tokr, Xg);
  if (FULLW)
    moe_cvt_w<<<(int)(2 * NW / 8 / 256), 256, 0, stream>>>(wi, wo, wiP, woP);

  hipFuncSetAttribute(reinterpret_cast<const void*>(&moe_g1<true>),
                      hipFuncAttributeMaxDynamicSharedMemorySize, LDS_G1);
  hipFuncSetAttribute(reinterpret_cast<const void*>(&moe_g1<false>),
                      hipFuncAttributeMaxDynamicSharedMemorySize, LDS_G1);
  hipFuncSetAttribute(reinterpret_cast<const void*>(&moe_g2<true>),
                      hipFuncAttributeMaxDynamicSharedMemorySize, LDS_G2);
  hipFuncSetAttribute(reinterpret_cast<const void*>(&moe_g2<false>),
                      hipFuncAttributeMaxDynamicSharedMemorySize, LDS_G2);

  const int KCH = W / 2;
  const int g1grid = MT2 * (W / 256);
  const int g2grid = MT2 * 8 * 2;
  const int cvtblk = (int)(((size_t)NE * W * D_MODEL / 8) / 256);

  for (int p = 0; p < FS; ++p) {
    const int f0 = p * W;
    if (!FULLW) {
      moe_cvt_wi_s<<<cvtblk, 256, 0, stream>>>(wi, wiP, W, f0);
      moe_cvt_wo_s<<<cvtblk, 256, 0, stream>>>(wo, woP, W, f0);
    }
    if (FULLW) {
      moe_g1<true><<<g1grid, 512, LDS_G1, stream>>>(Xg, wiP, te2, Hbuf, W, f0);
      moe_g2<true><<<g2grid, 512, LDS_G2, stream>>>(Hbuf, woP, te2, tokr, wrr,
                                                    out, W, f0, KCH);
    } else {
      moe_g1<false><<<g1grid, 512, LDS_G1, stream>>>(Xg, wiP, te2, Hbuf, W, f0);
      moe_g2<false><<<g2grid, 512, LDS_G2, stream>>>(Hbuf, woP, te2, tokr, wrr,
                                                     out, W, f0, KCH);
    }
  }
}